// Round 1
// baseline (4574.139 us; speedup 1.0000x reference)
//
#include <hip/hip_runtime.h>

#define NFULL 33024
#define FPS_T 512
#define FPS_J 65   // ceil(33024/512)

// ---- x1[b,o,k] = sum_i f[b,i] * ps_w[i,o,k] + ps_b[o] ; col = o*256+k ----
__global__ void k_ps(const float* __restrict__ feat,
                     const float* __restrict__ psw,
                     const float* __restrict__ psb,
                     float* __restrict__ out)
{
    __shared__ float fs[16384];   // all of f (32x512), 64 KB
    const int tid = threadIdx.x;
    for (int k = tid; k < 16384; k += 256) fs[k] = feat[k];
    __syncthreads();
    const int col = blockIdx.x * 256 + tid;    // 0..32767
    float acc[32];
    #pragma unroll
    for (int b = 0; b < 32; ++b) acc[b] = 0.f;
    for (int i = 0; i < 512; i += 4) {
        const float w0 = psw[(i+0)*32768 + col];
        const float w1 = psw[(i+1)*32768 + col];
        const float w2 = psw[(i+2)*32768 + col];
        const float w3 = psw[(i+3)*32768 + col];
        #pragma unroll
        for (int b = 0; b < 32; ++b) {
            const float4 f4 = *(const float4*)&fs[b*512 + i];
            acc[b] += f4.x*w0 + f4.y*w1 + f4.z*w2 + f4.w*w3;
        }
    }
    const float bias = psb[col >> 8];
    #pragma unroll
    for (int b = 0; b < 32; ++b) out[b*32768 + col] = acc[b] + bias;
}

// ---- fb[wsel][b,o] = sum_{i<512} f[b,i] * w[o*640 + 128 + i]  (fr-fold) ----
__global__ void k_fb(const float* __restrict__ feat,
                     const float* __restrict__ wa, const float* __restrict__ wb,
                     const float* __restrict__ wc, const float* __restrict__ wd,
                     float* __restrict__ fb)
{
    const int tid = blockIdx.x * 256 + threadIdx.x;  // 0..16383
    const int wsel = tid >> 12;
    const int r = tid & 4095;
    const int b = r >> 7, o = r & 127;
    const float* w = (wsel == 0 ? wa : wsel == 1 ? wb : wsel == 2 ? wc : wd) + o*640 + 128;
    const float* f = feat + b*512;
    float acc = 0.f;
    for (int i = 0; i < 512; i += 4) {
        const float4 wv = *(const float4*)(w + i);
        const float4 fv = *(const float4*)(f + i);
        acc += wv.x*fv.x + wv.y*fv.y + wv.z*fv.z + wv.w*fv.w;
    }
    fb[tid] = acc;
}

// ---- out[b,o,n] = relu?( sum_i w[o,i]*x[b,i,n] + bias[o] + fb[b,o] + add[b,o,n] )
__global__ void k_conv(const float* __restrict__ x,
                       const float* __restrict__ w,
                       const float* __restrict__ bias,
                       const float* __restrict__ fb,
                       const float* __restrict__ add,
                       float* __restrict__ out,
                       const int O, const int K, const int ldw, const int relu)
{
    const int bo = blockIdx.x;
    const int b = bo / O;
    const int o = bo - b * O;
    const int n = threadIdx.x;
    const float* __restrict__ wr = w + o * ldw;
    const float* __restrict__ xb = x + (b * K) * 256 + n;
    float acc = 0.f;
    for (int i = 0; i < K; i += 4) {
        const float4 wv = *(const float4*)(wr + i);
        acc += wv.x * xb[(i+0) << 8];
        acc += wv.y * xb[(i+1) << 8];
        acc += wv.z * xb[(i+2) << 8];
        acc += wv.w * xb[(i+3) << 8];
    }
    acc += bias[o];
    if (fb)   acc += fb[b * O + o];
    if (add)  acc += add[bo * 256 + n];
    if (relu) acc = fmaxf(acc, 0.f);
    out[bo * 256 + n] = acc;
}

// ---- pcd transpose -> d_out and points[0:256) ; also mirrors into P ----
__global__ void k_pcd(const float* __restrict__ comp,
                      float* __restrict__ pcd_out,
                      float* __restrict__ P)
{
    const int tid = blockIdx.x * 256 + threadIdx.x;  // 0..8191
    const int b = tid >> 8, n = tid & 255;
    const float cx = comp[(b*3+0)*256 + n];
    const float cy = comp[(b*3+1)*256 + n];
    const float cz = comp[(b*3+2)*256 + n];
    pcd_out[tid*3+0] = cx; pcd_out[tid*3+1] = cy; pcd_out[tid*3+2] = cz;
    const int pb = b*99072 + n*3;
    P[pb+0] = cx; P[pb+1] = cy; P[pb+2] = cz;
}

// ---- copy partial into P[256:33024) per batch (bitwise) ----
__global__ void k_copy(const float* __restrict__ partial, float* __restrict__ P)
{
    for (int idx = blockIdx.x*256 + threadIdx.x; idx < 32*32768*3; idx += gridDim.x*256) {
        const int b = idx / 98304;          // 32768*3
        const int r = idx - b*98304;
        P[b*99072 + 768 + r] = partial[idx];
    }
}

// ---- farthest point sampling: one block per batch, np-exact arithmetic ----
__launch_bounds__(FPS_T, 2)
__global__ void k_fps(const float* __restrict__ P, float* __restrict__ outp)
{
    __shared__ float zs[33280];   // z coords (padded), 130 KB
    __shared__ float redv[8];
    __shared__ int   redi[8];
    __shared__ int   lastidx_s;

    const int b = blockIdx.x;
    const int t = threadIdx.x;
    const float* __restrict__ Pb = P + b * 99072;
    const float NEG = -__builtin_inff();

    float px[FPS_J], py[FPS_J], d[FPS_J];
    #pragma unroll
    for (int j = 0; j < FPS_J; ++j) {
        const int p = j*FPS_T + t;
        if (p < NFULL) {
            px[j] = Pb[p*3+0];
            py[j] = Pb[p*3+1];
            zs[p] = Pb[p*3+2];
            d[j]  = 1.0e10f;
        } else {
            px[j] = 0.f; py[j] = 0.f;
            zs[p] = 0.f;              // p < 33280, in-bounds pad
            d[j]  = NEG;
        }
    }
    __syncthreads();

    int last = 0;
    float* __restrict__ po = outp + b * (512*3);
    for (int s = 0; s < 512; ++s) {
        const float lx = Pb[last*3+0];
        const float ly = Pb[last*3+1];
        const float lz = Pb[last*3+2];
        if (t == 0) { po[s*3+0] = lx; po[s*3+1] = ly; po[s*3+2] = lz; }
        if (s == 511) break;

        float bestv = NEG;
        int   besti = 0x7FFFFFFF;
        #pragma unroll
        for (int j = 0; j < FPS_J; ++j) {
            const float zj = zs[j*FPS_T + t];
            const float dx = __fsub_rn(px[j], lx);
            const float dy = __fsub_rn(py[j], ly);
            const float dz = __fsub_rn(zj,  lz);
            // np order: (dx*dx + dy*dy) + dz*dz, no fma contraction
            const float dist = __fadd_rn(__fadd_rn(__fmul_rn(dx,dx), __fmul_rn(dy,dy)),
                                         __fmul_rn(dz,dz));
            const float dj = fminf(d[j], dist);
            d[j] = dj;
            if (dj > bestv) { bestv = dj; besti = j*FPS_T + t; }  // first-max wins (j asc = idx asc)
        }
        // wave (64-lane) argmax reduce, min-index tie-break
        #pragma unroll
        for (int m = 1; m < 64; m <<= 1) {
            const float ov = __shfl_xor(bestv, m, 64);
            const int   oi = __shfl_xor(besti, m, 64);
            if (ov > bestv || (ov == bestv && oi < besti)) { bestv = ov; besti = oi; }
        }
        if ((t & 63) == 0) { redv[t >> 6] = bestv; redi[t >> 6] = besti; }
        __syncthreads();
        if (t < 64) {
            float v = (t < 8) ? redv[t] : NEG;
            int   i = (t < 8) ? redi[t] : 0x7FFFFFFF;
            #pragma unroll
            for (int m = 1; m < 8; m <<= 1) {
                const float ov = __shfl_xor(v, m, 64);
                const int   oi = __shfl_xor(i, m, 64);
                if (ov > v || (ov == v && oi < i)) { v = ov; i = oi; }
            }
            if (t == 0) lastidx_s = i;
        }
        __syncthreads();
        last = lastidx_s;
    }
}

extern "C" void kernel_launch(void* const* d_in, const int* in_sizes, int n_in,
                              void* d_out, int out_size, void* d_ws, size_t ws_size,
                              hipStream_t stream)
{
    const float* feat    = (const float*)d_in[0];
    const float* partial = (const float*)d_in[1];
    const float* ps_w    = (const float*)d_in[2];
    const float* ps_b    = (const float*)d_in[3];
    const float* m1_w1   = (const float*)d_in[4];
    const float* m1_b1   = (const float*)d_in[5];
    const float* m1_w2   = (const float*)d_in[6];
    const float* m1_b2   = (const float*)d_in[7];
    const float* m1_ws   = (const float*)d_in[8];
    const float* m1_bs   = (const float*)d_in[9];
    const float* m2_w1   = (const float*)d_in[10];
    const float* m2_b1   = (const float*)d_in[11];
    const float* m2_w2   = (const float*)d_in[12];
    const float* m2_b2   = (const float*)d_in[13];
    const float* m2_ws   = (const float*)d_in[14];
    const float* m2_bs   = (const float*)d_in[15];
    const float* m3_w1   = (const float*)d_in[16];
    const float* m3_b1   = (const float*)d_in[17];
    const float* m3_w2   = (const float*)d_in[18];
    const float* m3_b2   = (const float*)d_in[19];
    const float* m3_ws   = (const float*)d_in[20];
    const float* m3_bs   = (const float*)d_in[21];
    const float* m4_w1   = (const float*)d_in[22];
    const float* m4_b1   = (const float*)d_in[23];
    const float* m4_w2   = (const float*)d_in[24];
    const float* m4_b2   = (const float*)d_in[25];

    float* ws = (float*)d_ws;
    float* P  = ws;               // 32*33024*3 = 3,170,304 floats
    float* A  = ws + 3170304;     // 1,048,576
    float* B  = ws + 4218880;     // 1,048,576
    float* C  = ws + 5267456;     // 1,048,576
    float* FB = ws + 6316032;     // 4*4096 (m1_w1, m1_ws, m3_w1, m3_ws folds)

    float* out = (float*)d_out;   // [0,24576) pcd ; [24576,73728) p0

    k_ps  <<<128,  256, 0, stream>>>(feat, ps_w, ps_b, A);
    k_fb  <<<64,   256, 0, stream>>>(feat, m1_w1, m1_ws, m3_w1, m3_ws, FB);
    k_copy<<<2048, 256, 0, stream>>>(partial, P);

    // m1 (fr folded into FB)
    k_conv<<<32*128, 256, 0, stream>>>(A, m1_w1, m1_b1, FB,       nullptr, B, 128, 128, 640, 1);
    k_conv<<<32*128, 256, 0, stream>>>(A, m1_ws, m1_bs, FB+4096,  nullptr, C, 128, 128, 640, 0);
    k_conv<<<32*128, 256, 0, stream>>>(B, m1_w2, m1_b2, nullptr,  C,       A, 128, 128, 128, 0);
    // m2
    k_conv<<<32*64,  256, 0, stream>>>(A, m2_w1, m2_b1, nullptr,  nullptr, B, 64,  128, 128, 1);
    k_conv<<<32*128, 256, 0, stream>>>(A, m2_ws, m2_bs, nullptr,  nullptr, C, 128, 128, 128, 0);
    k_conv<<<32*128, 256, 0, stream>>>(B, m2_w2, m2_b2, nullptr,  C,       A, 128, 64,  64,  0);
    // m3 (fr folded)
    k_conv<<<32*128, 256, 0, stream>>>(A, m3_w1, m3_b1, FB+8192,  nullptr, B, 128, 128, 640, 1);
    k_conv<<<32*128, 256, 0, stream>>>(A, m3_ws, m3_bs, FB+12288, nullptr, C, 128, 128, 640, 0);
    k_conv<<<32*128, 256, 0, stream>>>(B, m3_w2, m3_b2, nullptr,  C,       A, 128, 128, 128, 0);
    // m4
    k_conv<<<32*64,  256, 0, stream>>>(A, m4_w1, m4_b1, nullptr,  nullptr, B, 64,  128, 128, 1);
    k_conv<<<32*3,   256, 0, stream>>>(B, m4_w2, m4_b2, nullptr,  nullptr, C, 3,   64,  64,  0);

    k_pcd <<<32, 256, 0, stream>>>(C, out, P);
    k_fps <<<32, FPS_T, 0, stream>>>(P, out + 24576);
}

// Round 2
// 4569.452 us; speedup vs baseline: 1.0010x; 1.0010x over previous
//
#include <hip/hip_runtime.h>

#define NFULL 33024
#define FPS_T 512
#define FPS_J 65   // ceil(33024/512)

// ---- x1[b,o,k] = sum_i f[b,i] * ps_w[i,o,k] + ps_b[o] ; col = o*256+k ----
__global__ void k_ps(const float* __restrict__ feat,
                     const float* __restrict__ psw,
                     const float* __restrict__ psb,
                     float* __restrict__ out)
{
    __shared__ float fs[16384];   // all of f (32x512), 64 KB
    const int tid = threadIdx.x;
    for (int k = tid; k < 16384; k += 256) fs[k] = feat[k];
    __syncthreads();
    const int col = blockIdx.x * 256 + tid;    // 0..32767
    float acc[32];
    #pragma unroll
    for (int b = 0; b < 32; ++b) acc[b] = 0.f;
    for (int i = 0; i < 512; i += 4) {
        const float w0 = psw[(i+0)*32768 + col];
        const float w1 = psw[(i+1)*32768 + col];
        const float w2 = psw[(i+2)*32768 + col];
        const float w3 = psw[(i+3)*32768 + col];
        #pragma unroll
        for (int b = 0; b < 32; ++b) {
            const float4 f4 = *(const float4*)&fs[b*512 + i];
            acc[b] += f4.x*w0 + f4.y*w1 + f4.z*w2 + f4.w*w3;
        }
    }
    const float bias = psb[col >> 8];
    #pragma unroll
    for (int b = 0; b < 32; ++b) out[b*32768 + col] = acc[b] + bias;
}

// ---- fb[wsel][b,o] = sum_{i<512} f[b,i] * w[o*640 + 128 + i]  (fr-fold) ----
__global__ void k_fb(const float* __restrict__ feat,
                     const float* __restrict__ wa, const float* __restrict__ wb,
                     const float* __restrict__ wc, const float* __restrict__ wd,
                     float* __restrict__ fb)
{
    const int tid = blockIdx.x * 256 + threadIdx.x;  // 0..16383
    const int wsel = tid >> 12;
    const int r = tid & 4095;
    const int b = r >> 7, o = r & 127;
    const float* w = (wsel == 0 ? wa : wsel == 1 ? wb : wsel == 2 ? wc : wd) + o*640 + 128;
    const float* f = feat + b*512;
    float acc = 0.f;
    for (int i = 0; i < 512; i += 4) {
        const float4 wv = *(const float4*)(w + i);
        const float4 fv = *(const float4*)(f + i);
        acc += wv.x*fv.x + wv.y*fv.y + wv.z*fv.z + wv.w*fv.w;
    }
    fb[tid] = acc;
}

// ---- out[b,o,n] = relu?( sum_i w[o,i]*x[b,i,n] + bias[o] + fb[b,o] + add[b,o,n] )
__global__ void k_conv(const float* __restrict__ x,
                       const float* __restrict__ w,
                       const float* __restrict__ bias,
                       const float* __restrict__ fb,
                       const float* __restrict__ add,
                       float* __restrict__ out,
                       const int O, const int K, const int ldw, const int relu)
{
    const int bo = blockIdx.x;
    const int b = bo / O;
    const int o = bo - b * O;
    const int n = threadIdx.x;
    const float* __restrict__ wr = w + o * ldw;
    const float* __restrict__ xb = x + (b * K) * 256 + n;
    float acc = 0.f;
    for (int i = 0; i < K; i += 4) {
        const float4 wv = *(const float4*)(wr + i);
        acc += wv.x * xb[(i+0) << 8];
        acc += wv.y * xb[(i+1) << 8];
        acc += wv.z * xb[(i+2) << 8];
        acc += wv.w * xb[(i+3) << 8];
    }
    acc += bias[o];
    if (fb)   acc += fb[b * O + o];
    if (add)  acc += add[bo * 256 + n];
    if (relu) acc = fmaxf(acc, 0.f);
    out[bo * 256 + n] = acc;
}

// ---- pcd transpose -> d_out and points[0:256) ; also mirrors into P ----
__global__ void k_pcd(const float* __restrict__ comp,
                      float* __restrict__ pcd_out,
                      float* __restrict__ P)
{
    const int tid = blockIdx.x * 256 + threadIdx.x;  // 0..8191
    const int b = tid >> 8, n = tid & 255;
    const float cx = comp[(b*3+0)*256 + n];
    const float cy = comp[(b*3+1)*256 + n];
    const float cz = comp[(b*3+2)*256 + n];
    pcd_out[tid*3+0] = cx; pcd_out[tid*3+1] = cy; pcd_out[tid*3+2] = cz;
    const int pb = b*99072 + n*3;
    P[pb+0] = cx; P[pb+1] = cy; P[pb+2] = cz;
}

// ---- copy partial into P[256:33024) per batch (bitwise) ----
__global__ void k_copy(const float* __restrict__ partial, float* __restrict__ P)
{
    for (int idx = blockIdx.x*256 + threadIdx.x; idx < 32*32768*3; idx += gridDim.x*256) {
        const int b = idx / 98304;          // 32768*3
        const int r = idx - b*98304;
        P[b*99072 + 768 + r] = partial[idx];
    }
}

// ---- farthest point sampling: one block per batch, np-exact arithmetic ----
// launch_bounds(512,1): min 1 wave/EU -> VGPR cap 512; the ~195-reg px/py/d
// arrays stay in registers (128-cap previously forced scratch spills, 8us/step)
__launch_bounds__(FPS_T, 1)
__global__ void k_fps(const float* __restrict__ P, float* __restrict__ outp)
{
    __shared__ float zs[33280];   // z coords (padded), 130 KB
    __shared__ float redv[8];
    __shared__ int   redi[8];
    __shared__ int   lastidx_s;

    const int b = blockIdx.x;
    const int t = threadIdx.x;
    const float* __restrict__ Pb = P + b * 99072;
    const float NEG = -__builtin_inff();

    float px[FPS_J], py[FPS_J], d[FPS_J];
    #pragma unroll
    for (int j = 0; j < FPS_J; ++j) {
        const int p = j*FPS_T + t;
        if (p < NFULL) {
            px[j] = Pb[p*3+0];
            py[j] = Pb[p*3+1];
            zs[p] = Pb[p*3+2];
            d[j]  = 1.0e10f;
        } else {
            px[j] = 0.f; py[j] = 0.f;
            zs[p] = 0.f;              // p < 33280, in-bounds pad
            d[j]  = NEG;
        }
    }
    __syncthreads();

    int last = 0;
    float* __restrict__ po = outp + b * (512*3);
    for (int s = 0; s < 512; ++s) {
        const float lx = Pb[last*3+0];
        const float ly = Pb[last*3+1];
        const float lz = Pb[last*3+2];
        if (t == 0) { po[s*3+0] = lx; po[s*3+1] = ly; po[s*3+2] = lz; }
        if (s == 511) break;

        float bestv = NEG;
        int   besti = 0x7FFFFFFF;
        #pragma unroll
        for (int j = 0; j < FPS_J; ++j) {
            const float zj = zs[j*FPS_T + t];
            const float dx = __fsub_rn(px[j], lx);
            const float dy = __fsub_rn(py[j], ly);
            const float dz = __fsub_rn(zj,  lz);
            // np order: (dx*dx + dy*dy) + dz*dz, no fma contraction
            const float dist = __fadd_rn(__fadd_rn(__fmul_rn(dx,dx), __fmul_rn(dy,dy)),
                                         __fmul_rn(dz,dz));
            const float dj = fminf(d[j], dist);
            d[j] = dj;
            if (dj > bestv) { bestv = dj; besti = j*FPS_T + t; }  // first-max wins (j asc = idx asc)
        }
        // wave (64-lane) argmax reduce, min-index tie-break
        #pragma unroll
        for (int m = 1; m < 64; m <<= 1) {
            const float ov = __shfl_xor(bestv, m, 64);
            const int   oi = __shfl_xor(besti, m, 64);
            if (ov > bestv || (ov == bestv && oi < besti)) { bestv = ov; besti = oi; }
        }
        if ((t & 63) == 0) { redv[t >> 6] = bestv; redi[t >> 6] = besti; }
        __syncthreads();
        if (t < 64) {
            float v = (t < 8) ? redv[t] : NEG;
            int   i = (t < 8) ? redi[t] : 0x7FFFFFFF;
            #pragma unroll
            for (int m = 1; m < 8; m <<= 1) {
                const float ov = __shfl_xor(v, m, 64);
                const int   oi = __shfl_xor(i, m, 64);
                if (ov > v || (ov == v && oi < i)) { v = ov; i = oi; }
            }
            if (t == 0) lastidx_s = i;
        }
        __syncthreads();
        last = lastidx_s;
    }
}

extern "C" void kernel_launch(void* const* d_in, const int* in_sizes, int n_in,
                              void* d_out, int out_size, void* d_ws, size_t ws_size,
                              hipStream_t stream)
{
    const float* feat    = (const float*)d_in[0];
    const float* partial = (const float*)d_in[1];
    const float* ps_w    = (const float*)d_in[2];
    const float* ps_b    = (const float*)d_in[3];
    const float* m1_w1   = (const float*)d_in[4];
    const float* m1_b1   = (const float*)d_in[5];
    const float* m1_w2   = (const float*)d_in[6];
    const float* m1_b2   = (const float*)d_in[7];
    const float* m1_ws   = (const float*)d_in[8];
    const float* m1_bs   = (const float*)d_in[9];
    const float* m2_w1   = (const float*)d_in[10];
    const float* m2_b1   = (const float*)d_in[11];
    const float* m2_w2   = (const float*)d_in[12];
    const float* m2_b2   = (const float*)d_in[13];
    const float* m2_ws   = (const float*)d_in[14];
    const float* m2_bs   = (const float*)d_in[15];
    const float* m3_w1   = (const float*)d_in[16];
    const float* m3_b1   = (const float*)d_in[17];
    const float* m3_w2   = (const float*)d_in[18];
    const float* m3_b2   = (const float*)d_in[19];
    const float* m3_ws   = (const float*)d_in[20];
    const float* m3_bs   = (const float*)d_in[21];
    const float* m4_w1   = (const float*)d_in[22];
    const float* m4_b1   = (const float*)d_in[23];
    const float* m4_w2   = (const float*)d_in[24];
    const float* m4_b2   = (const float*)d_in[25];

    float* ws = (float*)d_ws;
    float* P  = ws;               // 32*33024*3 = 3,170,304 floats
    float* A  = ws + 3170304;     // 1,048,576
    float* B  = ws + 4218880;     // 1,048,576
    float* C  = ws + 5267456;     // 1,048,576
    float* FB = ws + 6316032;     // 4*4096 (m1_w1, m1_ws, m3_w1, m3_ws folds)

    float* out = (float*)d_out;   // [0,24576) pcd ; [24576,73728) p0

    k_ps  <<<128,  256, 0, stream>>>(feat, ps_w, ps_b, A);
    k_fb  <<<64,   256, 0, stream>>>(feat, m1_w1, m1_ws, m3_w1, m3_ws, FB);
    k_copy<<<2048, 256, 0, stream>>>(partial, P);

    // m1 (fr folded into FB)
    k_conv<<<32*128, 256, 0, stream>>>(A, m1_w1, m1_b1, FB,       nullptr, B, 128, 128, 640, 1);
    k_conv<<<32*128, 256, 0, stream>>>(A, m1_ws, m1_bs, FB+4096,  nullptr, C, 128, 128, 640, 0);
    k_conv<<<32*128, 256, 0, stream>>>(B, m1_w2, m1_b2, nullptr,  C,       A, 128, 128, 128, 0);
    // m2
    k_conv<<<32*64,  256, 0, stream>>>(A, m2_w1, m2_b1, nullptr,  nullptr, B, 64,  128, 128, 1);
    k_conv<<<32*128, 256, 0, stream>>>(A, m2_ws, m2_bs, nullptr,  nullptr, C, 128, 128, 128, 0);
    k_conv<<<32*128, 256, 0, stream>>>(B, m2_w2, m2_b2, nullptr,  C,       A, 128, 64,  64,  0);
    // m3 (fr folded)
    k_conv<<<32*128, 256, 0, stream>>>(A, m3_w1, m3_b1, FB+8192,  nullptr, B, 128, 128, 640, 1);
    k_conv<<<32*128, 256, 0, stream>>>(A, m3_ws, m3_bs, FB+12288, nullptr, C, 128, 128, 640, 0);
    k_conv<<<32*128, 256, 0, stream>>>(B, m3_w2, m3_b2, nullptr,  C,       A, 128, 128, 128, 0);
    // m4
    k_conv<<<32*64,  256, 0, stream>>>(A, m4_w1, m4_b1, nullptr,  nullptr, B, 64,  128, 128, 1);
    k_conv<<<32*3,   256, 0, stream>>>(B, m4_w2, m4_b2, nullptr,  nullptr, C, 3,   64,  64,  0);

    k_pcd <<<32, 256, 0, stream>>>(C, out, P);
    k_fps <<<32, FPS_T, 0, stream>>>(P, out + 24576);
}

// Round 3
// 4449.278 us; speedup vs baseline: 1.0281x; 1.0270x over previous
//
#include <hip/hip_runtime.h>

#define NFULL 33024
#define FPS_T 512

// ---- x1[b,o,k] = sum_i f[b,i] * ps_w[i,o,k] + ps_b[o] ; col = o*256+k ----
__global__ void k_ps(const float* __restrict__ feat,
                     const float* __restrict__ psw,
                     const float* __restrict__ psb,
                     float* __restrict__ out)
{
    __shared__ float fs[16384];   // all of f (32x512), 64 KB
    const int tid = threadIdx.x;
    for (int k = tid; k < 16384; k += 256) fs[k] = feat[k];
    __syncthreads();
    const int col = blockIdx.x * 256 + tid;    // 0..32767
    float acc[32];
    #pragma unroll
    for (int b = 0; b < 32; ++b) acc[b] = 0.f;
    for (int i = 0; i < 512; i += 4) {
        const float w0 = psw[(i+0)*32768 + col];
        const float w1 = psw[(i+1)*32768 + col];
        const float w2 = psw[(i+2)*32768 + col];
        const float w3 = psw[(i+3)*32768 + col];
        #pragma unroll
        for (int b = 0; b < 32; ++b) {
            const float4 f4 = *(const float4*)&fs[b*512 + i];
            acc[b] += f4.x*w0 + f4.y*w1 + f4.z*w2 + f4.w*w3;
        }
    }
    const float bias = psb[col >> 8];
    #pragma unroll
    for (int b = 0; b < 32; ++b) out[b*32768 + col] = acc[b] + bias;
}

// ---- fb[wsel][b,o] = sum_{i<512} f[b,i] * w[o*640 + 128 + i]  (fr-fold) ----
__global__ void k_fb(const float* __restrict__ feat,
                     const float* __restrict__ wa, const float* __restrict__ wb,
                     const float* __restrict__ wc, const float* __restrict__ wd,
                     float* __restrict__ fb)
{
    const int tid = blockIdx.x * 256 + threadIdx.x;  // 0..16383
    const int wsel = tid >> 12;
    const int r = tid & 4095;
    const int b = r >> 7, o = r & 127;
    const float* w = (wsel == 0 ? wa : wsel == 1 ? wb : wsel == 2 ? wc : wd) + o*640 + 128;
    const float* f = feat + b*512;
    float acc = 0.f;
    for (int i = 0; i < 512; i += 4) {
        const float4 wv = *(const float4*)(w + i);
        const float4 fv = *(const float4*)(f + i);
        acc += wv.x*fv.x + wv.y*fv.y + wv.z*fv.z + wv.w*fv.w;
    }
    fb[tid] = acc;
}

// ---- out[b,o,n] = relu?( sum_i w[o,i]*x[b,i,n] + bias[o] + fb[b,o] + add[b,o,n] )
__global__ void k_conv(const float* __restrict__ x,
                       const float* __restrict__ w,
                       const float* __restrict__ bias,
                       const float* __restrict__ fb,
                       const float* __restrict__ add,
                       float* __restrict__ out,
                       const int O, const int K, const int ldw, const int relu)
{
    const int bo = blockIdx.x;
    const int b = bo / O;
    const int o = bo - b * O;
    const int n = threadIdx.x;
    const float* __restrict__ wr = w + o * ldw;
    const float* __restrict__ xb = x + (b * K) * 256 + n;
    float acc = 0.f;
    for (int i = 0; i < K; i += 4) {
        const float4 wv = *(const float4*)(wr + i);
        acc += wv.x * xb[(i+0) << 8];
        acc += wv.y * xb[(i+1) << 8];
        acc += wv.z * xb[(i+2) << 8];
        acc += wv.w * xb[(i+3) << 8];
    }
    acc += bias[o];
    if (fb)   acc += fb[b * O + o];
    if (add)  acc += add[bo * 256 + n];
    if (relu) acc = fmaxf(acc, 0.f);
    out[bo * 256 + n] = acc;
}

// ---- pcd transpose -> d_out and points[0:256) ; also mirrors into P ----
__global__ void k_pcd(const float* __restrict__ comp,
                      float* __restrict__ pcd_out,
                      float* __restrict__ P)
{
    const int tid = blockIdx.x * 256 + threadIdx.x;  // 0..8191
    const int b = tid >> 8, n = tid & 255;
    const float cx = comp[(b*3+0)*256 + n];
    const float cy = comp[(b*3+1)*256 + n];
    const float cz = comp[(b*3+2)*256 + n];
    pcd_out[tid*3+0] = cx; pcd_out[tid*3+1] = cy; pcd_out[tid*3+2] = cz;
    const int pb = b*99072 + n*3;
    P[pb+0] = cx; P[pb+1] = cy; P[pb+2] = cz;
}

// ---- copy partial into P[256:33024) per batch (bitwise) ----
__global__ void k_copy(const float* __restrict__ partial, float* __restrict__ P)
{
    for (int idx = blockIdx.x*256 + threadIdx.x; idx < 32*32768*3; idx += gridDim.x*256) {
        const int b = idx / 98304;          // 32768*3
        const int r = idx - b*98304;
        P[b*99072 + 768 + r] = partial[idx];
    }
}

// ================= farthest point sampling =================
// One block per batch. Per-thread state as NAMED SCALARS (macro-generated):
// arrays + #pragma unroll left the state runtime-indexed -> scratch spills
// (VGPR=128, 4.6MB spill writes, 8.2us/step). Named scalars cannot spill to
// scratch via SROA failure; ~220 VGPR fits the 256 cap of a 512-thread block.

#define REP64(M) \
  M(0) M(1) M(2) M(3) M(4) M(5) M(6) M(7) M(8) M(9) \
  M(10) M(11) M(12) M(13) M(14) M(15) M(16) M(17) M(18) M(19) \
  M(20) M(21) M(22) M(23) M(24) M(25) M(26) M(27) M(28) M(29) \
  M(30) M(31) M(32) M(33) M(34) M(35) M(36) M(37) M(38) M(39) \
  M(40) M(41) M(42) M(43) M(44) M(45) M(46) M(47) M(48) M(49) \
  M(50) M(51) M(52) M(53) M(54) M(55) M(56) M(57) M(58) M(59) \
  M(60) M(61) M(62) M(63)

#define FPS_DECL(i) float px##i, py##i, d##i;

#define FPS_INIT(i) { \
    const int p = (i)*FPS_T + t; \
    px##i = Pb[p*3+0]; py##i = Pb[p*3+1]; zs[p] = Pb[p*3+2]; d##i = 1.0e10f; }

#define FPS_BODY(i) { \
    const float zj = zs[(i)*FPS_T + t]; \
    const float dx = __fsub_rn(px##i, lx); \
    const float dy = __fsub_rn(py##i, ly); \
    const float dz = __fsub_rn(zj,  lz); \
    const float dist = __fadd_rn(__fadd_rn(__fmul_rn(dx,dx), __fmul_rn(dy,dy)), \
                                 __fmul_rn(dz,dz)); \
    const float dj = fminf(d##i, dist); \
    d##i = dj; \
    if (dj > bestv) { bestv = dj; besti = (i)*FPS_T + t; } }

__launch_bounds__(FPS_T, 2)
__global__ void k_fps(const float* __restrict__ P, float* __restrict__ outp)
{
    __shared__ float zs[33280];   // z coords (padded), 130 KB
    __shared__ float redv[8];
    __shared__ int   redi[8];
    __shared__ int   lastidx_s;

    const int b = blockIdx.x;
    const int t = threadIdx.x;
    const float* __restrict__ Pb = P + b * 99072;
    const float NEG = -__builtin_inff();

    REP64(FPS_DECL)
    float px64, py64, d64;

    REP64(FPS_INIT)
    {   // j = 64: only t < 256 is a real point (64*512 + 256 = 33024)
        const int p = 64*FPS_T + t;
        if (t < (NFULL - 64*FPS_T)) {
            px64 = Pb[p*3+0]; py64 = Pb[p*3+1]; zs[p] = Pb[p*3+2]; d64 = 1.0e10f;
        } else {
            px64 = 0.f; py64 = 0.f; zs[p] = 0.f; d64 = NEG;   // p < 33280 pad
        }
    }
    __syncthreads();

    int last = 0;
    float* __restrict__ po = outp + b * (512*3);
    for (int s = 0; s < 512; ++s) {
        const float lx = Pb[last*3+0];
        const float ly = Pb[last*3+1];
        const float lz = Pb[last*3+2];
        if (t == 0) { po[s*3+0] = lx; po[s*3+1] = ly; po[s*3+2] = lz; }
        if (s == 511) break;

        float bestv = NEG;
        int   besti = 0x7FFFFFFF;
        // np order: dist = (dx*dx + dy*dy) + dz*dz, no fma contraction;
        // first-max wins (ascending j = ascending global index, strict >)
        REP64(FPS_BODY)
        FPS_BODY(64)

        // wave (64-lane) argmax reduce, min-index tie-break
        #pragma unroll
        for (int m = 1; m < 64; m <<= 1) {
            const float ov = __shfl_xor(bestv, m, 64);
            const int   oi = __shfl_xor(besti, m, 64);
            if (ov > bestv || (ov == bestv && oi < besti)) { bestv = ov; besti = oi; }
        }
        if ((t & 63) == 0) { redv[t >> 6] = bestv; redi[t >> 6] = besti; }
        __syncthreads();
        if (t < 64) {
            float v = (t < 8) ? redv[t] : NEG;
            int   i = (t < 8) ? redi[t] : 0x7FFFFFFF;
            #pragma unroll
            for (int m = 1; m < 8; m <<= 1) {
                const float ov = __shfl_xor(v, m, 64);
                const int   oi = __shfl_xor(i, m, 64);
                if (ov > v || (ov == v && oi < i)) { v = ov; i = oi; }
            }
            if (t == 0) lastidx_s = i;
        }
        __syncthreads();
        last = lastidx_s;
    }
}

extern "C" void kernel_launch(void* const* d_in, const int* in_sizes, int n_in,
                              void* d_out, int out_size, void* d_ws, size_t ws_size,
                              hipStream_t stream)
{
    const float* feat    = (const float*)d_in[0];
    const float* partial = (const float*)d_in[1];
    const float* ps_w    = (const float*)d_in[2];
    const float* ps_b    = (const float*)d_in[3];
    const float* m1_w1   = (const float*)d_in[4];
    const float* m1_b1   = (const float*)d_in[5];
    const float* m1_w2   = (const float*)d_in[6];
    const float* m1_b2   = (const float*)d_in[7];
    const float* m1_ws   = (const float*)d_in[8];
    const float* m1_bs   = (const float*)d_in[9];
    const float* m2_w1   = (const float*)d_in[10];
    const float* m2_b1   = (const float*)d_in[11];
    const float* m2_w2   = (const float*)d_in[12];
    const float* m2_b2   = (const float*)d_in[13];
    const float* m2_ws   = (const float*)d_in[14];
    const float* m2_bs   = (const float*)d_in[15];
    const float* m3_w1   = (const float*)d_in[16];
    const float* m3_b1   = (const float*)d_in[17];
    const float* m3_w2   = (const float*)d_in[18];
    const float* m3_b2   = (const float*)d_in[19];
    const float* m3_ws   = (const float*)d_in[20];
    const float* m3_bs   = (const float*)d_in[21];
    const float* m4_w1   = (const float*)d_in[22];
    const float* m4_b1   = (const float*)d_in[23];
    const float* m4_w2   = (const float*)d_in[24];
    const float* m4_b2   = (const float*)d_in[25];

    float* ws = (float*)d_ws;
    float* P  = ws;               // 32*33024*3 = 3,170,304 floats
    float* A  = ws + 3170304;     // 1,048,576
    float* B  = ws + 4218880;     // 1,048,576
    float* C  = ws + 5267456;     // 1,048,576
    float* FB = ws + 6316032;     // 4*4096 (m1_w1, m1_ws, m3_w1, m3_ws folds)

    float* out = (float*)d_out;   // [0,24576) pcd ; [24576,73728) p0

    k_ps  <<<128,  256, 0, stream>>>(feat, ps_w, ps_b, A);
    k_fb  <<<64,   256, 0, stream>>>(feat, m1_w1, m1_ws, m3_w1, m3_ws, FB);
    k_copy<<<2048, 256, 0, stream>>>(partial, P);

    // m1 (fr folded into FB)
    k_conv<<<32*128, 256, 0, stream>>>(A, m1_w1, m1_b1, FB,       nullptr, B, 128, 128, 640, 1);
    k_conv<<<32*128, 256, 0, stream>>>(A, m1_ws, m1_bs, FB+4096,  nullptr, C, 128, 128, 640, 0);
    k_conv<<<32*128, 256, 0, stream>>>(B, m1_w2, m1_b2, nullptr,  C,       A, 128, 128, 128, 0);
    // m2
    k_conv<<<32*64,  256, 0, stream>>>(A, m2_w1, m2_b1, nullptr,  nullptr, B, 64,  128, 128, 1);
    k_conv<<<32*128, 256, 0, stream>>>(A, m2_ws, m2_bs, nullptr,  nullptr, C, 128, 128, 128, 0);
    k_conv<<<32*128, 256, 0, stream>>>(B, m2_w2, m2_b2, nullptr,  C,       A, 128, 64,  64,  0);
    // m3 (fr folded)
    k_conv<<<32*128, 256, 0, stream>>>(A, m3_w1, m3_b1, FB+8192,  nullptr, B, 128, 128, 640, 1);
    k_conv<<<32*128, 256, 0, stream>>>(A, m3_ws, m3_bs, FB+12288, nullptr, C, 128, 128, 640, 0);
    k_conv<<<32*128, 256, 0, stream>>>(B, m3_w2, m3_b2, nullptr,  C,       A, 128, 128, 128, 0);
    // m4
    k_conv<<<32*64,  256, 0, stream>>>(A, m4_w1, m4_b1, nullptr,  nullptr, B, 64,  128, 128, 1);
    k_conv<<<32*3,   256, 0, stream>>>(B, m4_w2, m4_b2, nullptr,  nullptr, C, 3,   64,  64,  0);

    k_pcd <<<32, 256, 0, stream>>>(C, out, P);
    k_fps <<<32, FPS_T, 0, stream>>>(P, out + 24576);
}